// Round 8
// baseline (30.381 us; speedup 1.0000x reference)
//
#include <hip/hip_runtime.h>

// Problem constants (match reference):
//   B = 8192 batches, N = 64 antennas, K = 16 users, NOISE = 1.0
//   H: [B, N, K, 2] f32  (re/im interleaved, 32 floats per n-row)
//   P: [B, 2*N*K]  f32  (first N*K = Pr[n][j], second N*K = Pi[n][j])
// Output: scalar f32 = -(1/B) * sum_{b,k} log2(1 + sig/interf)
//
// R8: persistent-wave depth-2 pipeline. R5/R6/R7 all converged at ~27us
// with every pipe idle -> exposed load latency, once per wave, 8192 waves.
// Now 1024 long-lived waves x 8 batches each; per iteration a wave issues
// the NEXT batch's 16 global_load_lds (fire-and-forget, zero VGPR) and
// waits with counted vmcnt(16) -- the prefetch stays in flight across the
// entire compute phase, so latency is hidden structurally. Wave-private
// double buffer => no s_barrier at all. Complex 16x16x64 matmul per batch
// via 8 x mfma_f32_16x16x32_bf16 (C/D: col=lane&15, row=4*(lane>>4)+reg).

typedef short bf16x8 __attribute__((ext_vector_type(8)));
typedef float f32x4  __attribute__((ext_vector_type(4)));
typedef int   i32x4  __attribute__((ext_vector_type(4)));

__device__ __forceinline__ int pk2(float lo, float hi) {
    int r;
    asm("v_cvt_pk_bf16_f32 %0, %1, %2" : "=v"(r) : "v"(lo), "v"(hi));
    return r;   // bf16(lo) low 16b, bf16(hi) high 16b (RNE)
}

__device__ __forceinline__ bf16x8 mk8(const float* v) {  // v[8] -> packed bf16 frag
    i32x4 t;
    #pragma unroll
    for (int i = 0; i < 4; ++i) t[i] = pk2(v[2 * i], v[2 * i + 1]);
    return __builtin_bit_cast(bf16x8, t);
}

__device__ __forceinline__ bf16x8 negbf(bf16x8 a) {      // flip all 8 sign bits
    i32x4 t = __builtin_bit_cast(i32x4, a);
    #pragma unroll
    for (int i = 0; i < 4; ++i) t[i] ^= 0x80008000;
    return __builtin_bit_cast(bf16x8, t);
}

__device__ __forceinline__ void gload16(const float* g, float* s) {
    __builtin_amdgcn_global_load_lds(
        (const __attribute__((address_space(1))) void*)g,
        (__attribute__((address_space(3))) void*)s,
        16, 0, 0);
}

#define MFMA __builtin_amdgcn_mfma_f32_16x16x32_bf16

// Stage one batch (H 8KB + P 8KB) into a 16KB LDS buffer: 16 x 1KB DMA.
__device__ __forceinline__ void stage(const float* gH, const float* gP,
                                      float* dst, int lane) {
    #pragma unroll
    for (int ii = 0; ii < 8; ++ii)
        gload16(gH + ii * 256 + lane * 4, dst + ii * 256);
    #pragma unroll
    for (int ii = 0; ii < 8; ++ii)
        gload16(gP + ii * 256 + lane * 4, dst + 2048 + ii * 256);
}

// Full per-batch computation from a staged 16KB buffer; returns the batch's
// sum-rate, identical across all 64 lanes.
__device__ __forceinline__ float computeBatch(const float* buf,
                                              int j, int g, int n0) {
    // ---- H -> A fragments ----
    float ar0[8], ai0[8], ar1[8], ai1[8];
    #pragma unroll
    for (int r = 0; r < 8; ++r) {
        const float2 h0 = *reinterpret_cast<const float2*>(buf + (n0 + r) * 32 + 2 * j);
        const float2 h1 = *reinterpret_cast<const float2*>(buf + (n0 + r + 32) * 32 + 2 * j);
        ar0[r] = h0.x; ai0[r] = h0.y;
        ar1[r] = h1.x; ai1[r] = h1.y;
    }
    // ---- P -> B fragments ----
    const float* bp = buf + 2048;
    float pr0[8], pr1[8], pi0[8], pi1[8];
    #pragma unroll
    for (int r = 0; r < 8; ++r) {
        pr0[r] = bp[(n0 + r) * 16 + j];
        pr1[r] = bp[(n0 + r + 32) * 16 + j];
        pi0[r] = bp[1024 + (n0 + r) * 16 + j];
        pi1[r] = bp[1024 + (n0 + r + 32) * 16 + j];
    }
    const bf16x8 Ahr0 = mk8(ar0), Ahr1 = mk8(ar1);
    const bf16x8 Ahi0 = mk8(ai0), Ahi1 = mk8(ai1);
    const bf16x8 Bpr0 = mk8(pr0), Bpr1 = mk8(pr1);
    const bf16x8 Bpi0 = mk8(pi0), Bpi1 = mk8(pi1);

    // ---- Complex 16x16x64 matmul: Dr = HrPr - HiPi, Di = HrPi + HiPr ----
    f32x4 dr = {0.f, 0.f, 0.f, 0.f}, di = {0.f, 0.f, 0.f, 0.f};
    dr = MFMA(Ahr0, Bpr0, dr, 0, 0, 0);
    dr = MFMA(Ahr1, Bpr1, dr, 0, 0, 0);
    dr = MFMA(negbf(Ahi0), Bpi0, dr, 0, 0, 0);
    dr = MFMA(negbf(Ahi1), Bpi1, dr, 0, 0, 0);
    di = MFMA(Ahr0, Bpi0, di, 0, 0, 0);
    di = MFMA(Ahr1, Bpi1, di, 0, 0, 0);
    di = MFMA(Ahi0, Bpr0, di, 0, 0, 0);
    di = MFMA(Ahi1, Bpr1, di, 0, 0, 0);

    // ---- Epilogue: C/D layout col=j=lane&15, row=k=4*g+reg ----
    float tot[4], sig[4];
    #pragma unroll
    for (int r = 0; r < 4; ++r) {
        const float mag = dr[r] * dr[r] + di[r] * di[r];
        const int k = g * 4 + r;
        tot[r] = mag;
        sig[r] = (j == k) ? mag : 0.0f;
    }
    #pragma unroll
    for (int m = 1; m < 16; m <<= 1) {
        #pragma unroll
        for (int r = 0; r < 4; ++r) {
            tot[r] += __shfl_xor(tot[r], m, 64);
            sig[r] += __shfl_xor(sig[r], m, 64);
        }
    }
    float rate = 0.0f;
    #pragma unroll
    for (int r = 0; r < 4; ++r)
        rate += log2f(1.0f + sig[r] / (tot[r] - sig[r] + 1.0f));
    rate += __shfl_xor(rate, 16, 64);
    rate += __shfl_xor(rate, 32, 64);
    return rate;
}

__global__ __launch_bounds__(128, 1) void sumrate_kernel(
        const float* __restrict__ H, const float* __restrict__ P,
        float* __restrict__ ws) {
    // 2 waves x 2 buffers x 16KB = 64KB/block -> 2 blocks/CU
    __shared__ float sBuf[2][2][4096];

    const int w    = threadIdx.x >> 6;
    const int lane = threadIdx.x & 63;
    const int gw   = blockIdx.x * 2 + w;      // global wave id, 0..1023
    const int j    = lane & 15;               // A row (k) and B col (j)
    const int g    = lane >> 4;               // n-slice group 0..3
    const int n0   = g * 8;

    const float* gH = H + (size_t)gw * 8 * 2048;   // this wave's 8 batches
    const float* gP = P + (size_t)gw * 8 * 2048;

    // Prologue: stage batch 0 into buffer 0.
    stage(gH, gP, &sBuf[w][0][0], lane);

    float rateAcc = 0.0f;
    #pragma unroll
    for (int i = 0; i < 8; ++i) {
        // Issue next batch's DMA before waiting on the current one.
        if (i < 7)
            stage(gH + (i + 1) * 2048, gP + (i + 1) * 2048,
                  &sBuf[w][(i + 1) & 1][0], lane);
        // Counted wait: current batch's 16 loads done, prefetch stays in flight.
        if (i < 7) asm volatile("s_waitcnt vmcnt(16)" ::: "memory");
        else       asm volatile("s_waitcnt vmcnt(0)"  ::: "memory");
        __builtin_amdgcn_sched_barrier(0);
        rateAcc += computeBatch(&sBuf[w][i & 1][0], j, g, n0);
        __builtin_amdgcn_sched_barrier(0);
    }

    if (lane == 0) ws[gw] = rateAcc;   // 1024 plain stores, no contention
}

// One block reduces the 1024 per-wave rate sums and writes the scalar loss.
__global__ __launch_bounds__(1024) void reduce_kernel(
        const float* __restrict__ ws, float* __restrict__ out) {
    __shared__ float sPart[16];
    float s = ws[threadIdx.x];

    #pragma unroll
    for (int m = 1; m < 64; m <<= 1)
        s += __shfl_xor(s, m, 64);

    const int w = threadIdx.x >> 6;
    const int l = threadIdx.x & 63;
    if (l == 0) sPart[w] = s;
    __syncthreads();

    if (w == 0) {
        float t = (l < 16) ? sPart[l] : 0.0f;
        #pragma unroll
        for (int m = 1; m < 16; m <<= 1)
            t += __shfl_xor(t, m, 64);
        if (l == 0) out[0] = t * (-1.0f / 8192.0f);
    }
}

extern "C" void kernel_launch(void* const* d_in, const int* in_sizes, int n_in,
                              void* d_out, int out_size, void* d_ws, size_t ws_size,
                              hipStream_t stream) {
    const float* H = (const float*)d_in[0];
    const float* P = (const float*)d_in[1];
    float* out = (float*)d_out;
    float* ws  = (float*)d_ws;   // 1024 floats of per-wave rate sums

    // 1024 persistent waves (512 blocks x 2 waves), 8 batches each.
    sumrate_kernel<<<512, 128, 0, stream>>>(H, P, ws);
    reduce_kernel<<<1, 1024, 0, stream>>>(ws, out);
}

// Round 9
// 27.129 us; speedup vs baseline: 1.1198x; 1.1198x over previous
//
#include <hip/hip_runtime.h>

// Problem constants (match reference):
//   B = 8192 batches, N = 64 antennas, K = 16 users, NOISE = 1.0
//   H: [B, N, K, 2] f32  (re/im interleaved, 32 floats per n-row)
//   P: [B, 2*N*K]  f32  (first N*K = Pr[n][j], second N*K = Pi[n][j])
// Output: scalar f32 = -(1/B) * sum_{b,k} log2(1 + sig/interf)
//
// R9: main kernel = R6 verbatim (best: 27.0us). Model: per-CU VMEM delivery
// rate ~10 B/cyc/CU (m13: 6.29 TB/s / 256 CU / 2.4 GHz) bounds sumrate at
// ~21.4us; R5/R6/R7 all sit at ~23-24us (~90%). Remaining slack is the
// second dispatch: shrink reduce to one 128-thread block with float4 loads.
// Same-address atomics / cooperative sync are worse (R0-R2: ~14.6ns/atomic).

typedef short bf16x8 __attribute__((ext_vector_type(8)));
typedef float f32x4  __attribute__((ext_vector_type(4)));
typedef int   i32x4  __attribute__((ext_vector_type(4)));

__device__ __forceinline__ int pk2(float lo, float hi) {
    int r;
    asm("v_cvt_pk_bf16_f32 %0, %1, %2" : "=v"(r) : "v"(lo), "v"(hi));
    return r;   // bf16(lo) low 16b, bf16(hi) high 16b (RNE)
}

__device__ __forceinline__ bf16x8 mk8(const float* v) {  // v[8] -> packed bf16 frag
    i32x4 t;
    #pragma unroll
    for (int i = 0; i < 4; ++i) t[i] = pk2(v[2 * i], v[2 * i + 1]);
    return __builtin_bit_cast(bf16x8, t);
}

__device__ __forceinline__ bf16x8 negbf(bf16x8 a) {      // flip all 8 sign bits
    i32x4 t = __builtin_bit_cast(i32x4, a);
    #pragma unroll
    for (int i = 0; i < 4; ++i) t[i] ^= 0x80008000;
    return __builtin_bit_cast(bf16x8, t);
}

#define MFMA __builtin_amdgcn_mfma_f32_16x16x32_bf16

__global__ __launch_bounds__(256, 4) void sumrate_kernel(
        const float* __restrict__ H, const float* __restrict__ P,
        float* __restrict__ ws) {
    __shared__ float sRate[4];

    const int wave = threadIdx.x >> 6;        // 4 waves/block, 1 batch each
    const int lane = threadIdx.x & 63;
    const int b    = blockIdx.x * 4 + wave;
    const int j    = lane & 15;               // A row (k) and B col (j)
    const int g    = lane >> 4;               // n-slice group 0..3
    const int n0   = g * 8;                   // this lane's base n

    const float* Hb = H + (size_t)b * 2048;
    const float* Pb = P + (size_t)b * 2048;
    const float* hA = Hb + n0 * 32 + 2 * j;   // (re,im) of H[n][k], n-stride 32 f
    const float* pB = Pb + n0 * 16 + j;       // Pr[n][j], n-stride 16 f

    // ---- Global loads: every byte exactly once, coalesced ----
    float2 h0[8], h1[8];                      // H halves (n 0..31 / 32..63)
    float pr0[8], pr1[8], pi0[8], pi1[8];     // P halves, re/im
    #pragma unroll
    for (int r = 0; r < 8; ++r) {
        h0[r] = *reinterpret_cast<const float2*>(hA + r * 32);
        h1[r] = *reinterpret_cast<const float2*>(hA + 1024 + r * 32);
        pr0[r] = pB[r * 16];
        pr1[r] = pB[512 + r * 16];
        pi0[r] = pB[1024 + r * 16];
        pi1[r] = pB[1536 + r * 16];
    }

    // ---- Pack bf16 fragments (A and B use the identical (lane,reg)->n map) ----
    float ar0[8], ai0[8], ar1[8], ai1[8];
    #pragma unroll
    for (int r = 0; r < 8; ++r) {
        ar0[r] = h0[r].x; ai0[r] = h0[r].y;
        ar1[r] = h1[r].x; ai1[r] = h1[r].y;
    }
    const bf16x8 Ahr0 = mk8(ar0), Ahr1 = mk8(ar1);
    const bf16x8 Ahi0 = mk8(ai0), Ahi1 = mk8(ai1);
    const bf16x8 Bpr0 = mk8(pr0), Bpr1 = mk8(pr1);
    const bf16x8 Bpi0 = mk8(pi0), Bpi1 = mk8(pi1);

    // ---- Complex 16x16x64 matmul: Dr = HrPr - HiPi, Di = HrPi + HiPr ----
    f32x4 dr = {0.f, 0.f, 0.f, 0.f}, di = {0.f, 0.f, 0.f, 0.f};
    dr = MFMA(Ahr0, Bpr0, dr, 0, 0, 0);
    dr = MFMA(Ahr1, Bpr1, dr, 0, 0, 0);
    dr = MFMA(negbf(Ahi0), Bpi0, dr, 0, 0, 0);
    dr = MFMA(negbf(Ahi1), Bpi1, dr, 0, 0, 0);
    di = MFMA(Ahr0, Bpi0, di, 0, 0, 0);
    di = MFMA(Ahr1, Bpi1, di, 0, 0, 0);
    di = MFMA(Ahi0, Bpr0, di, 0, 0, 0);
    di = MFMA(Ahi1, Bpr1, di, 0, 0, 0);

    // ---- Epilogue: C/D layout col=j=lane&15, row=k=4*g+reg ----
    float tot[4], sig[4];
    #pragma unroll
    for (int r = 0; r < 4; ++r) {
        const float mag = dr[r] * dr[r] + di[r] * di[r];
        const int k = g * 4 + r;
        tot[r] = mag;
        sig[r] = (j == k) ? mag : 0.0f;
    }
    // Row-sum over j: reduce across the 16 lanes of this g-group (low 4 bits).
    #pragma unroll
    for (int m = 1; m < 16; m <<= 1) {
        #pragma unroll
        for (int r = 0; r < 4; ++r) {
            tot[r] += __shfl_xor(tot[r], m, 64);
            sig[r] += __shfl_xor(sig[r], m, 64);
        }
    }
    // rate for this group's 4 k's (identical across the 16 lanes of the group)
    float rate = 0.0f;
    #pragma unroll
    for (int r = 0; r < 4; ++r)
        rate += log2f(1.0f + sig[r] / (tot[r] - sig[r] + 1.0f));
    // Sum the 4 groups (lane bits 4..5); each group's value counted once.
    rate += __shfl_xor(rate, 16, 64);
    rate += __shfl_xor(rate, 32, 64);

    // Combine the block's 4 per-batch rates -> one store per block.
    if (lane == 0) sRate[wave] = rate;
    __syncthreads();
    if (threadIdx.x == 0)
        ws[blockIdx.x] = sRate[0] + sRate[1] + sRate[2] + sRate[3];
}

// One 128-thread block reduces the 2048 per-block partials (float4 loads).
__global__ __launch_bounds__(128) void reduce_kernel(
        const float* __restrict__ ws, float* __restrict__ out) {
    __shared__ float sPart[2];
    // 128 lanes x 4 float4 = 2048 floats
    const float4* w4 = reinterpret_cast<const float4*>(ws);
    float s = 0.0f;
    #pragma unroll
    for (int i = 0; i < 4; ++i) {
        const float4 v = w4[threadIdx.x + i * 128];
        s += (v.x + v.y) + (v.z + v.w);
    }
    #pragma unroll
    for (int m = 1; m < 64; m <<= 1)
        s += __shfl_xor(s, m, 64);

    const int w = threadIdx.x >> 6;
    const int l = threadIdx.x & 63;
    if (l == 0) sPart[w] = s;
    __syncthreads();
    if (threadIdx.x == 0)
        out[0] = (sPart[0] + sPart[1]) * (-1.0f / 8192.0f);
}

extern "C" void kernel_launch(void* const* d_in, const int* in_sizes, int n_in,
                              void* d_out, int out_size, void* d_ws, size_t ws_size,
                              hipStream_t stream) {
    const float* H = (const float*)d_in[0];
    const float* P = (const float*)d_in[1];
    float* out = (float*)d_out;
    float* ws  = (float*)d_ws;   // 2048 floats of per-block rate sums

    // 8192 batches, 1 wave per batch, 4 waves (batches) per 256-thread block
    sumrate_kernel<<<8192 / 4, 256, 0, stream>>>(H, P, ws);
    reduce_kernel<<<1, 128, 0, stream>>>(ws, out);
}